// Round 3
// baseline (307.677 us; speedup 1.0000x reference)
//
#include <hip/hip_runtime.h>

#define Hd    256
#define OUTD  10
#define DDEP  64
#define TLEN  8192
#define NBLK  256
#define NTHR  512

// Module-scope barrier counters: zero-initialized once at module load, then
// monotonically increasing across all calls/replays (no reset needed; the
// generation is recovered from the fetched value). 6 barriers used.
__device__ unsigned g_cnt[8];

__device__ __forceinline__ void grid_barrier(int i, int tid)
{
    __syncthreads();                       // all block stores issued & drained
    if (tid == 0) {
        __threadfence();                   // release: flush XCD L2 (agent scope)
        const unsigned t = atomicAdd(&g_cnt[i], 1u);
        const unsigned target = (t / NBLK + 1u) * NBLK;
        int guard = 0;
        while (__hip_atomic_load(&g_cnt[i], __ATOMIC_ACQUIRE,
                                 __HIP_MEMORY_SCOPE_AGENT) < target) {
            __builtin_amdgcn_s_sleep(2);
            if (++guard > 4000000) break;  // safety valve: fail loud, not hang
        }
        __threadfence();                   // acquire: invalidate stale L1/L2
    }
    __syncthreads();
}

// Stage s (0..5): blocks [0,32) square P; blocks [32, 32+rowB) compute
// Rdst[j] = Rsrc[j] * Psrc (8 rows each) and the fused K-dots with w1.
__device__ __forceinline__ void do_stage(
    int s, const float* __restrict__ W2, const float* __restrict__ W3,
    const float* __restrict__ w1, float* Pb0, float* Pb1,
    float* Rb, float* Kb, float* smem, int bid, int tid)
{
    if (s == 0 && bid == 100 && tid < 128)         // zero K padding lanes
        Kb[(tid >> 1) * 12 + 10 + (tid & 1)] = 0.0f;

    const int rRows = 10 << s;                      // rows produced this stage
    const int sqB   = (s < 5) ? 32 : 0;
    const int rowB  = (rRows + 7) >> 3;
    const bool isSQ  = bid < sqB;
    const bool isRow = !isSQ && (bid < sqB + rowB);
    if (!isSQ && !isRow) return;

    const float* Psrc = (s == 0) ? W2 : ((s & 1) ? Pb0 : Pb1);
    float*       Pdst = (s & 1) ? Pb1 : Pb0;

    const int j0 = (isSQ ? bid : bid - sqB) * 8;
    const int nr = isSQ ? 8 : min(8, rRows - j0);
    const float* X = isSQ ? (Psrc + j0 * Hd)
                          : ((s == 0) ? (W3 + j0 * Hd) : (Rb + j0 * Hd));
    float* Out = isSQ ? (Pdst + j0 * Hd) : (Rb + (rRows + j0) * Hd);

    float* Xs  = smem;            // [8][256]
    float* red = smem + 2048;     // [8][256], reused for K partials

    const int c = tid & 255;
    const int h = tid >> 8;       // j-half 0/1

    for (int i = tid; i < 8 * Hd; i += NTHR) {
        const int r = i >> 8;
        Xs[i] = (r < nr) ? X[r * Hd + (i & 255)] : 0.0f;
    }
    __syncthreads();

    float acc[8] = {0.f,0.f,0.f,0.f,0.f,0.f,0.f,0.f};
    const float* Bc = Psrc + c + (h * 128) * Hd;
    #pragma unroll 2
    for (int j = 0; j < 128; j += 8) {
        float p[8];
        #pragma unroll
        for (int k = 0; k < 8; ++k) p[k] = Bc[(j + k) * Hd];
        #pragma unroll
        for (int r = 0; r < 8; ++r) {
            const float* xr = Xs + r * Hd + h * 128 + j;
            const float4 xa = *(const float4*)xr;
            const float4 xb = *(const float4*)(xr + 4);
            acc[r] = fmaf(xa.x, p[0], acc[r]);
            acc[r] = fmaf(xa.y, p[1], acc[r]);
            acc[r] = fmaf(xa.z, p[2], acc[r]);
            acc[r] = fmaf(xa.w, p[3], acc[r]);
            acc[r] = fmaf(xb.x, p[4], acc[r]);
            acc[r] = fmaf(xb.y, p[5], acc[r]);
            acc[r] = fmaf(xb.z, p[6], acc[r]);
            acc[r] = fmaf(xb.w, p[7], acc[r]);
        }
    }

    if (h == 1) {
        #pragma unroll
        for (int r = 0; r < 8; ++r) red[r * Hd + c] = acc[r];
    }
    __syncthreads();
    if (h == 0) {
        #pragma unroll
        for (int r = 0; r < 8; ++r) acc[r] += red[r * Hd + c];
        for (int r = 0; r < nr; ++r) Out[r * Hd + c] = acc[r];
        if (s == 0 && isRow)                        // copy W3 -> R0
            for (int r = 0; r < nr; ++r) Rb[(j0 + r) * Hd + c] = Xs[r * Hd + c];
    }
    if (!isRow) return;                             // block-uniform

    // K[rid] = Out_row . w1 for produced rows
    __syncthreads();                                // red reuse barrier
    const float w1c = w1[c];
    if (h == 0) {
        #pragma unroll
        for (int r = 0; r < 8; ++r) {
            float v = acc[r] * w1c;
            #pragma unroll
            for (int off = 32; off; off >>= 1) v += __shfl_down(v, off);
            if ((tid & 63) == 0) red[r * 4 + (tid >> 6)] = v;
        }
    }
    __syncthreads();
    if (tid < nr) {
        const int rid = rRows + j0 + tid;
        const float kv = red[tid * 4] + red[tid * 4 + 1] +
                         red[tid * 4 + 2] + red[tid * 4 + 3];
        Kb[(rid / 10) * 12 + rid % 10] = kv;
    }

    if (s == 0) {                                   // K[0..9] from W3 rows
        __syncthreads();
        if (h == 0) {
            #pragma unroll
            for (int r = 0; r < 8; ++r) {
                float v = Xs[r * Hd + c] * w1c;
                #pragma unroll
                for (int off = 32; off; off >>= 1) v += __shfl_down(v, off);
                if ((tid & 63) == 0) red[r * 4 + (tid >> 6)] = v;
            }
        }
        __syncthreads();
        if (tid < nr) {
            const int rid = j0 + tid;
            const float kv = red[tid * 4] + red[tid * 4 + 1] +
                             red[tid * 4 + 2] + red[tid * 4 + 3];
            Kb[(rid / 10) * 12 + rid % 10] = kv;
        }
    }
}

// Causal FIR after the final barrier: y[b,t,o] = sum_{d<64} K[d][o]*x[b,t-d].
__device__ __forceinline__ void conv_phase(
    const float* __restrict__ x, const float* __restrict__ Kb,
    float* __restrict__ y, float* smem, int bid, int tid)
{
    float* xs = smem;             // swizzled: phys(j) = j + (j>>5), j < 2112
    float* Ks = smem + 2200;      // 768 floats
    const int b  = bid >> 2;
    const int t0 = (bid & 3) * 2048;
    const float* xb = x + b * TLEN;

    for (int j = tid; j < 2112; j += NTHR) {
        const int g = t0 - 64 + j;
        xs[j + (j >> 5)] = (g >= 0) ? xb[g] : 0.0f;
    }
    for (int j = tid; j < DDEP * 12; j += NTHR) Ks[j] = Kb[j];
    __syncthreads();

    const int ub = tid * 4;
    float acc[4][OUTD];
    #pragma unroll
    for (int i = 0; i < 4; ++i)
        #pragma unroll
        for (int o = 0; o < OUTD; ++o) acc[i][o] = 0.0f;

    float wn[4];
    #pragma unroll
    for (int i = 0; i < 4; ++i) {
        const int j = 64 + ub + i;
        wn[i] = xs[j + (j >> 5)];
    }

    #pragma unroll 8
    for (int d = 0; d < DDEP; ++d) {
        const float4 kA = *(const float4*)&Ks[d * 12];
        const float4 kB = *(const float4*)&Ks[d * 12 + 4];
        const float2 kC = *(const float2*)&Ks[d * 12 + 8];
        #pragma unroll
        for (int i = 0; i < 4; ++i) {
            const float xv = wn[i];
            acc[i][0] = fmaf(kA.x, xv, acc[i][0]);
            acc[i][1] = fmaf(kA.y, xv, acc[i][1]);
            acc[i][2] = fmaf(kA.z, xv, acc[i][2]);
            acc[i][3] = fmaf(kA.w, xv, acc[i][3]);
            acc[i][4] = fmaf(kB.x, xv, acc[i][4]);
            acc[i][5] = fmaf(kB.y, xv, acc[i][5]);
            acc[i][6] = fmaf(kB.z, xv, acc[i][6]);
            acc[i][7] = fmaf(kB.w, xv, acc[i][7]);
            acc[i][8] = fmaf(kC.x, xv, acc[i][8]);
            acc[i][9] = fmaf(kC.y, xv, acc[i][9]);
        }
        const int jn = 64 + ub - 1 - d;
        const float nw = xs[jn + (jn >> 5)];
        wn[3] = wn[2]; wn[2] = wn[1]; wn[1] = wn[0]; wn[0] = nw;
    }

    float buf[4 * OUTD];
    #pragma unroll
    for (int i = 0; i < 4; ++i)
        #pragma unroll
        for (int o = 0; o < OUTD; ++o) buf[i * OUTD + o] = acc[i][o];

    float* yb = y + (size_t)(b * TLEN + t0 + ub) * OUTD;
    #pragma unroll
    for (int q = 0; q < 10; ++q)
        *(float4*)(yb + q * 4) =
            make_float4(buf[4 * q], buf[4 * q + 1], buf[4 * q + 2], buf[4 * q + 3]);
}

__global__ __launch_bounds__(NTHR, 1) void fused_rnn_kernel(
    const float* __restrict__ x, const float* __restrict__ w1,
    const float* __restrict__ W2, const float* __restrict__ W3,
    float* __restrict__ y,
    float* Pb0, float* Pb1, float* Rb, float* Kb)
{
    __shared__ float smem[4224];
    const int tid = threadIdx.x, bid = blockIdx.x;

    #pragma unroll 1
    for (int s = 0; s < 6; ++s) {
        if (s) grid_barrier(s - 1, tid);
        do_stage(s, W2, W3, w1, Pb0, Pb1, Rb, Kb, smem, bid, tid);
    }
    grid_barrier(5, tid);
    conv_phase(x, Kb, y, smem, bid, tid);
}

extern "C" void kernel_launch(void* const* d_in, const int* in_sizes, int n_in,
                              void* d_out, int out_size, void* d_ws, size_t ws_size,
                              hipStream_t stream)
{
    const float* x  = (const float*)d_in[0];   // (64, 8192)
    const float* w1 = (const float*)d_in[1];   // (256, 1) contiguous
    const float* W2 = (const float*)d_in[2];   // (256, 256)
    const float* W3 = (const float*)d_in[3];   // (10, 256)
    float* y  = (float*)d_out;
    float* ws = (float*)d_ws;

    float* Pb0 = ws;                    // 65536 floats
    float* Pb1 = ws + 65536;            // 65536 floats
    float* Rb  = ws + 131072;           // 640 rows x 256
    float* Kb  = ws + 131072 + 163840;  // 64 x 12

    fused_rnn_kernel<<<NBLK, dim3(NTHR), 0, stream>>>(
        x, w1, W2, W3, y, Pb0, Pb1, Rb, Kb);
}

// Round 4
// 112.494 us; speedup vs baseline: 2.7351x; 2.7351x over previous
//
#include <hip/hip_runtime.h>

#define Hd    256
#define OUTD  10
#define DDEP  32
#define TLEN  8192
#define NBLK  256
#define NTHR  512

// Module-scope barrier counters: zero-init at load, monotonically increasing
// across replays (generation recovered from fetched value; no reset needed).
__device__ unsigned g_cnt[8];

__device__ __forceinline__ void grid_barrier(int i, int tid)
{
    __syncthreads();                    // drains each thread's stores (vmcnt)
    if (tid == 0) {
        // release RMW: my block's stores visible at the coherent point
        const unsigned t = __hip_atomic_fetch_add(
            &g_cnt[i], 1u, __ATOMIC_RELEASE, __HIP_MEMORY_SCOPE_AGENT);
        const unsigned target = (t / NBLK + 1u) * NBLK;
        unsigned guard = 0;
        // RELAXED polling: read-through load, NO per-iteration cache inv
        while (__hip_atomic_load(&g_cnt[i], __ATOMIC_RELAXED,
                                 __HIP_MEMORY_SCOPE_AGENT) < target) {
            __builtin_amdgcn_s_sleep(8);
            if (++guard > 1000000u) break;   // safety valve
        }
        // single acquire: invalidate stale L1/L2 once
        (void)__hip_atomic_load(&g_cnt[i], __ATOMIC_ACQUIRE,
                                __HIP_MEMORY_SCOPE_AGENT);
    }
    __syncthreads();
}

// Stage s (0..4): blocks [0,sqB) square P (8 rows each); blocks [sqB, sqB+rowB)
// compute Rdst rows [10*2^s, 10*2^(s+1)) = Rsrc rows [0,10*2^s) * Psrc, plus
// fused K-dots with w1. s=0 also copies W3->R0 and K[0..9].
__device__ __forceinline__ void do_stage(
    int s, const float* __restrict__ W2, const float* __restrict__ W3,
    const float* __restrict__ w1, float* Pb0, float* Pb1,
    float* Rb, float* Kb, float* smem, int bid, int tid)
{
    if (s == 0 && bid == 100 && tid < 2 * DDEP)     // zero K padding lanes
        Kb[(tid >> 1) * 12 + 10 + (tid & 1)] = 0.0f;

    const int rRows = 10 << s;                      // rows produced this stage
    const int sqB   = (s < 4) ? 32 : 0;
    const int rowB  = (rRows + 7) >> 3;
    const bool isSQ  = bid < sqB;
    const bool isRow = !isSQ && (bid < sqB + rowB);
    if (!isSQ && !isRow) return;

    const float* Psrc = (s == 0) ? W2 : ((s & 1) ? Pb0 : Pb1);
    float*       Pdst = (s & 1) ? Pb1 : Pb0;

    const int j0 = (isSQ ? bid : bid - sqB) * 8;
    const int nr = isSQ ? 8 : min(8, rRows - j0);
    const float* X = isSQ ? (Psrc + j0 * Hd)
                          : ((s == 0) ? (W3 + j0 * Hd) : (Rb + j0 * Hd));
    float* Out = isSQ ? (Pdst + j0 * Hd) : (Rb + (rRows + j0) * Hd);

    float* Xs  = smem;            // [8][256]
    float* red = smem + 2048;     // [8][256], reused for K partials

    const int c = tid & 255;
    const int h = tid >> 8;       // j-half 0/1

    for (int i = tid; i < 8 * Hd; i += NTHR) {
        const int r = i >> 8;
        Xs[i] = (r < nr) ? X[r * Hd + (i & 255)] : 0.0f;
    }
    __syncthreads();

    float acc[8] = {0.f,0.f,0.f,0.f,0.f,0.f,0.f,0.f};
    const float* Bc = Psrc + c + (h * 128) * Hd;
    #pragma unroll 2
    for (int j = 0; j < 128; j += 8) {
        float p[8];
        #pragma unroll
        for (int k = 0; k < 8; ++k) p[k] = Bc[(j + k) * Hd];
        #pragma unroll
        for (int r = 0; r < 8; ++r) {
            const float* xr = Xs + r * Hd + h * 128 + j;
            const float4 xa = *(const float4*)xr;
            const float4 xb = *(const float4*)(xr + 4);
            acc[r] = fmaf(xa.x, p[0], acc[r]);
            acc[r] = fmaf(xa.y, p[1], acc[r]);
            acc[r] = fmaf(xa.z, p[2], acc[r]);
            acc[r] = fmaf(xa.w, p[3], acc[r]);
            acc[r] = fmaf(xb.x, p[4], acc[r]);
            acc[r] = fmaf(xb.y, p[5], acc[r]);
            acc[r] = fmaf(xb.z, p[6], acc[r]);
            acc[r] = fmaf(xb.w, p[7], acc[r]);
        }
    }

    if (h == 1) {
        #pragma unroll
        for (int r = 0; r < 8; ++r) red[r * Hd + c] = acc[r];
    }
    __syncthreads();
    if (h == 0) {
        #pragma unroll
        for (int r = 0; r < 8; ++r) acc[r] += red[r * Hd + c];
        for (int r = 0; r < nr; ++r) Out[r * Hd + c] = acc[r];
        if (s == 0 && isRow)                        // copy W3 -> R0
            for (int r = 0; r < nr; ++r) Rb[(j0 + r) * Hd + c] = Xs[r * Hd + c];
    }
    if (!isRow) return;                             // block-uniform

    // K[rid] = Out_row . w1 for produced rows
    __syncthreads();                                // red reuse barrier
    const float w1c = w1[c];
    if (h == 0) {
        #pragma unroll
        for (int r = 0; r < 8; ++r) {
            float v = acc[r] * w1c;
            #pragma unroll
            for (int off = 32; off; off >>= 1) v += __shfl_down(v, off);
            if ((tid & 63) == 0) red[r * 4 + (tid >> 6)] = v;
        }
    }
    __syncthreads();
    if (tid < nr) {
        const int rid = rRows + j0 + tid;
        const float kv = red[tid * 4] + red[tid * 4 + 1] +
                         red[tid * 4 + 2] + red[tid * 4 + 3];
        Kb[(rid / 10) * 12 + rid % 10] = kv;
    }

    if (s == 0) {                                   // K[0..9] from W3 rows
        __syncthreads();
        if (h == 0) {
            #pragma unroll
            for (int r = 0; r < 8; ++r) {
                float v = Xs[r * Hd + c] * w1c;
                #pragma unroll
                for (int off = 32; off; off >>= 1) v += __shfl_down(v, off);
                if ((tid & 63) == 0) red[r * 4 + (tid >> 6)] = v;
            }
        }
        __syncthreads();
        if (tid < nr) {
            const int rid = j0 + tid;
            const float kv = red[tid * 4] + red[tid * 4 + 1] +
                             red[tid * 4 + 2] + red[tid * 4 + 3];
            Kb[(rid / 10) * 12 + rid % 10] = kv;
        }
    }
}

// Causal FIR after the final barrier: y[b,t,o] = sum_{d<32} K[d][o]*x[b,t-d].
__device__ __forceinline__ void conv_phase(
    const float* __restrict__ x, const float* __restrict__ Kb,
    float* __restrict__ y, float* smem, int bid, int tid)
{
    float* xs = smem;             // swizzled: phys(j) = j + (j>>5), j < 2080
    float* Ks = smem + 2176;      // 384 floats, 16B-aligned
    const int b  = bid >> 2;
    const int t0 = (bid & 3) * 2048;
    const float* xb = x + b * TLEN;

    for (int j = tid; j < 2080; j += NTHR) {
        const int g = t0 - DDEP + j;
        xs[j + (j >> 5)] = (g >= 0) ? xb[g] : 0.0f;
    }
    for (int j = tid; j < DDEP * 12; j += NTHR) Ks[j] = Kb[j];
    __syncthreads();

    const int ub = tid * 4;
    float acc[4][OUTD];
    #pragma unroll
    for (int i = 0; i < 4; ++i)
        #pragma unroll
        for (int o = 0; o < OUTD; ++o) acc[i][o] = 0.0f;

    float wn[4];
    #pragma unroll
    for (int i = 0; i < 4; ++i) {
        const int j = DDEP + ub + i;
        wn[i] = xs[j + (j >> 5)];
    }

    #pragma unroll 8
    for (int d = 0; d < DDEP; ++d) {
        const float4 kA = *(const float4*)&Ks[d * 12];
        const float4 kB = *(const float4*)&Ks[d * 12 + 4];
        const float2 kC = *(const float2*)&Ks[d * 12 + 8];
        #pragma unroll
        for (int i = 0; i < 4; ++i) {
            const float xv = wn[i];
            acc[i][0] = fmaf(kA.x, xv, acc[i][0]);
            acc[i][1] = fmaf(kA.y, xv, acc[i][1]);
            acc[i][2] = fmaf(kA.z, xv, acc[i][2]);
            acc[i][3] = fmaf(kA.w, xv, acc[i][3]);
            acc[i][4] = fmaf(kB.x, xv, acc[i][4]);
            acc[i][5] = fmaf(kB.y, xv, acc[i][5]);
            acc[i][6] = fmaf(kB.z, xv, acc[i][6]);
            acc[i][7] = fmaf(kB.w, xv, acc[i][7]);
            acc[i][8] = fmaf(kC.x, xv, acc[i][8]);
            acc[i][9] = fmaf(kC.y, xv, acc[i][9]);
        }
        const int jn = DDEP + ub - 1 - d;
        const float nw = xs[jn + (jn >> 5)];
        wn[3] = wn[2]; wn[2] = wn[1]; wn[1] = wn[0]; wn[0] = nw;
    }

    float buf[4 * OUTD];
    #pragma unroll
    for (int i = 0; i < 4; ++i)
        #pragma unroll
        for (int o = 0; o < OUTD; ++o) buf[i * OUTD + o] = acc[i][o];

    float* yb = y + (size_t)(b * TLEN + t0 + ub) * OUTD;
    #pragma unroll
    for (int q = 0; q < 10; ++q)
        *(float4*)(yb + q * 4) =
            make_float4(buf[4 * q], buf[4 * q + 1], buf[4 * q + 2], buf[4 * q + 3]);
}

__global__ __launch_bounds__(NTHR, 1) void fused_rnn_kernel(
    const float* __restrict__ x, const float* __restrict__ w1,
    const float* __restrict__ W2, const float* __restrict__ W3,
    float* __restrict__ y,
    float* Pb0, float* Pb1, float* Rb, float* Kb)
{
    __shared__ float smem[4096];
    const int tid = threadIdx.x, bid = blockIdx.x;

    #pragma unroll 1
    for (int s = 0; s < 5; ++s) {
        if (s) grid_barrier(s - 1, tid);
        do_stage(s, W2, W3, w1, Pb0, Pb1, Rb, Kb, smem, bid, tid);
        if (s == 0 && bid >= 34) {
            // idle blocks: prime IF$/L2 with this block's conv x-window
            const int b = bid >> 2, t0 = (bid & 3) * 2048;
            const float* xb = x + b * TLEN;
            float sv = 0.f;
            for (int j = tid; j < 2080; j += NTHR) {
                const int g = t0 - DDEP + j;
                if (g >= 0) sv += xb[g];
            }
            asm volatile("" :: "v"(sv));   // keep loads live (rule #17)
        }
    }
    grid_barrier(4, tid);
    conv_phase(x, Kb, y, smem, bid, tid);
}

extern "C" void kernel_launch(void* const* d_in, const int* in_sizes, int n_in,
                              void* d_out, int out_size, void* d_ws, size_t ws_size,
                              hipStream_t stream)
{
    const float* x  = (const float*)d_in[0];   // (64, 8192)
    const float* w1 = (const float*)d_in[1];   // (256, 1) contiguous
    const float* W2 = (const float*)d_in[2];   // (256, 256)
    const float* W3 = (const float*)d_in[3];   // (10, 256)
    float* y  = (float*)d_out;
    float* ws = (float*)d_ws;

    float* Pb0 = ws;                    // 65536 floats
    float* Pb1 = ws + 65536;            // 65536 floats
    float* Rb  = ws + 131072;           // 320 rows x 256
    float* Kb  = ws + 131072 + 81920;   // 32 x 12

    fused_rnn_kernel<<<NBLK, dim3(NTHR), 0, stream>>>(
        x, w1, W2, W3, y, Pb0, Pb1, Rb, Kb);
}

// Round 5
// 45.823 us; speedup vs baseline: 6.7145x; 2.4550x over previous
//
#include <hip/hip_runtime.h>

#define Hd    256
#define OUTD  10
#define DDEP  32
#define TLEN  8192
#define NTHR  1024
#define NBLK  256

// LDS float offsets
#define OFF_VS   0            // Vs[32][256] = 8192
#define OFF_W3   8192         // W3s[10][256] = 2560
#define OFF_KS   10752        // Ks[32][12] = 384
#define OFF_XS   11136        // xs swizzled window, 2144
#define SMEM_FLOATS 13280     // 53.1 KB

__global__ __launch_bounds__(NTHR, 1) void fused_rnn_kernel(
    const float* __restrict__ x, const float* __restrict__ w1g,
    const float* __restrict__ W2, const float* __restrict__ W3,
    float* __restrict__ y)
{
    __shared__ float smem[SMEM_FLOATS];
    float* Vs  = smem + OFF_VS;
    float* W3s = smem + OFF_W3;
    float* Ks  = smem + OFF_KS;
    float* xs  = smem + OFF_XS;

    const int tid = threadIdx.x;
    const int bid = blockIdx.x;
    const int b   = bid >> 2;
    const int t0  = (bid & 3) * 2048;
    const float* xb = x + b * TLEN;

    // ---- stage x window (swizzled phys(j)=j+(j>>5)), W3, v0=w1 into LDS ----
    for (int j = tid; j < 2048 + DDEP; j += NTHR) {
        const int g = t0 - DDEP + j;
        xs[j + (j >> 5)] = (g >= 0) ? xb[g] : 0.0f;
    }
    for (int i = tid; i < OUTD * Hd; i += NTHR) W3s[i] = W3[i];
    if (tid < Hd) Vs[tid] = w1g[tid];

    // ---- W2 chunk into registers: thread t owns row r=t>>2, cols q*64..q*64+63.
    // Chunk k holds column-chunk m=(k+4q)&15 (bank-phase rotation; all register
    // indices compile-time -> stays in VGPRs, rule #20).
    const int r = tid >> 2, q = tid & 3;
    const float4* W2v = (const float4*)W2;
    float4 W2r[16];
    #pragma unroll
    for (int k = 0; k < 16; ++k)
        W2r[k] = W2v[(r * 4 + q) * 16 + ((k + 4 * q) & 15)];

    __syncthreads();

    // ---- v-chain: v_{d+1} = W2 * v_d; all v_d kept in Vs ----
    const float4* Vsv = (const float4*)Vs;
    #pragma unroll 1
    for (int d = 0; d < DDEP - 1; ++d) {
        const int vbase = d * 64 + q * 16;
        float4 acc = make_float4(0.f, 0.f, 0.f, 0.f);
        #pragma unroll
        for (int k = 0; k < 16; ++k) {
            const float4 vv = Vsv[vbase + ((k + 4 * q) & 15)];
            const float4 wv = W2r[k];
            acc.x = fmaf(wv.x, vv.x, acc.x);
            acc.y = fmaf(wv.y, vv.y, acc.y);
            acc.z = fmaf(wv.z, vv.z, acc.z);
            acc.w = fmaf(wv.w, vv.w, acc.w);
        }
        float p = (acc.x + acc.y) + (acc.z + acc.w);
        p += __shfl_xor(p, 1);
        p += __shfl_xor(p, 2);
        if (q == 0) Vs[(d + 1) * Hd + r] = p;
        __syncthreads();
    }

    // ---- K[d][o] = W3[o] . v_d  (32 d-groups x 32 lanes) ----
    {
        const int d = tid >> 5, l = tid & 31;
        const float* vd  = Vs + d * Hd + l * 8;
        float vloc[8];
        #pragma unroll
        for (int i = 0; i < 8; ++i) vloc[i] = vd[i];
        #pragma unroll
        for (int o = 0; o < OUTD; ++o) {
            const float* w3o = W3s + o * Hd + l * 8;
            float p = 0.f;
            #pragma unroll
            for (int i = 0; i < 8; ++i) p = fmaf(w3o[i], vloc[i], p);
            p += __shfl_xor(p, 1);
            p += __shfl_xor(p, 2);
            p += __shfl_xor(p, 4);
            p += __shfl_xor(p, 8);
            p += __shfl_xor(p, 16);
            if (l == 0) Ks[d * 12 + o] = p;
        }
        if (l == 1) { Ks[d * 12 + 10] = 0.f; Ks[d * 12 + 11] = 0.f; }
    }
    __syncthreads();

    // ---- causal FIR: y[b,t,o] = sum_{d<32} K[d][o] * x[b,t-d] ----
    const int ub = tid * 2;
    float acc0[OUTD], acc1[OUTD];
    #pragma unroll
    for (int o = 0; o < OUTD; ++o) { acc0[o] = 0.f; acc1[o] = 0.f; }

    float wn0, wn1;
    {
        const int j0 = DDEP + ub, j1 = DDEP + ub + 1;
        wn0 = xs[j0 + (j0 >> 5)];
        wn1 = xs[j1 + (j1 >> 5)];
    }

    #pragma unroll 8
    for (int d = 0; d < DDEP; ++d) {
        const float4 kA = *(const float4*)&Ks[d * 12];
        const float4 kB = *(const float4*)&Ks[d * 12 + 4];
        const float2 kC = *(const float2*)&Ks[d * 12 + 8];
        acc0[0] = fmaf(kA.x, wn0, acc0[0]);  acc1[0] = fmaf(kA.x, wn1, acc1[0]);
        acc0[1] = fmaf(kA.y, wn0, acc0[1]);  acc1[1] = fmaf(kA.y, wn1, acc1[1]);
        acc0[2] = fmaf(kA.z, wn0, acc0[2]);  acc1[2] = fmaf(kA.z, wn1, acc1[2]);
        acc0[3] = fmaf(kA.w, wn0, acc0[3]);  acc1[3] = fmaf(kA.w, wn1, acc1[3]);
        acc0[4] = fmaf(kB.x, wn0, acc0[4]);  acc1[4] = fmaf(kB.x, wn1, acc1[4]);
        acc0[5] = fmaf(kB.y, wn0, acc0[5]);  acc1[5] = fmaf(kB.y, wn1, acc1[5]);
        acc0[6] = fmaf(kB.z, wn0, acc0[6]);  acc1[6] = fmaf(kB.z, wn1, acc1[6]);
        acc0[7] = fmaf(kB.w, wn0, acc0[7]);  acc1[7] = fmaf(kB.w, wn1, acc1[7]);
        acc0[8] = fmaf(kC.x, wn0, acc0[8]);  acc1[8] = fmaf(kC.x, wn1, acc1[8]);
        acc0[9] = fmaf(kC.y, wn0, acc0[9]);  acc1[9] = fmaf(kC.y, wn1, acc1[9]);
        const int jn = DDEP + ub - 1 - d;
        wn1 = wn0;
        wn0 = xs[jn + (jn >> 5)];
    }

    float buf[2 * OUTD];
    #pragma unroll
    for (int o = 0; o < OUTD; ++o) { buf[o] = acc0[o]; buf[OUTD + o] = acc1[o]; }

    float* yb = y + (size_t)(b * TLEN + t0 + ub) * OUTD;  // 20 consecutive floats
    #pragma unroll
    for (int v = 0; v < 5; ++v)
        *(float4*)(yb + v * 4) =
            make_float4(buf[4 * v], buf[4 * v + 1], buf[4 * v + 2], buf[4 * v + 3]);
}

extern "C" void kernel_launch(void* const* d_in, const int* in_sizes, int n_in,
                              void* d_out, int out_size, void* d_ws, size_t ws_size,
                              hipStream_t stream)
{
    const float* x  = (const float*)d_in[0];   // (64, 8192)
    const float* w1 = (const float*)d_in[1];   // (256, 1) contiguous
    const float* W2 = (const float*)d_in[2];   // (256, 256)
    const float* W3 = (const float*)d_in[3];   // (10, 256)
    float* y  = (float*)d_out;

    fused_rnn_kernel<<<NBLK, dim3(NTHR), 0, stream>>>(x, w1, W2, W3, y);
}

// Round 6
// 36.792 us; speedup vs baseline: 8.3626x; 1.2455x over previous
//
#include <hip/hip_runtime.h>

#define Hd    256
#define OUTD  10
#define DDEP  16
#define TLEN  8192
#define NTHR  512
#define NBLK  256

// LDS float offsets
#define OFF_VS   0                        // Vs[DDEP][256] = 4096
#define OFF_W3   (DDEP * Hd)              // W3s[10][256] = 2560
#define OFF_KS   (OFF_W3 + OUTD * Hd)     // Ks[16][12] = 192
#define OFF_XS   (OFF_KS + DDEP * 12)     // xs swizzled window
#define XS_LOG   (2048 + DDEP)            // 2064 logical
#define XS_PHYS  (XS_LOG + (XS_LOG >> 5) + 8)
#define SMEM_FLOATS (OFF_XS + XS_PHYS)    // ~36 KB

__device__ __forceinline__ int ph(int j) { return j + (j >> 5); }

__global__ __launch_bounds__(NTHR, 2) void fused_rnn_kernel(
    const float* __restrict__ x, const float* __restrict__ w1g,
    const float* __restrict__ W2, const float* __restrict__ W3,
    float* __restrict__ y)
{
    __shared__ float smem[SMEM_FLOATS];
    float* Vs  = smem + OFF_VS;
    float* W3s = smem + OFF_W3;
    float* Ks  = smem + OFF_KS;
    float* xs  = smem + OFF_XS;

    const int tid = threadIdx.x;
    const int bid = blockIdx.x;
    const int b   = bid >> 2;
    const int t0  = (bid & 3) * 2048;
    const float* xb = x + b * TLEN;

    // ---- W2 into registers FIRST (deep global latency, hidden by staging).
    // Thread t owns rows {2rp, 2rp+1}, col quarter q*64..q*64+63.
    // Column-chunk rotation (k+4q)&15 spreads the 4 q-broadcast reads over
    // banks in the chain loop; all register indices compile-time (rule #20).
    const int rp = tid >> 2, q = tid & 3;
    const float4* W2v = (const float4*)W2;
    float4 A0[16], A1[16];
    #pragma unroll
    for (int k = 0; k < 16; ++k) {
        const int m = (k + 4 * q) & 15;
        A0[k] = W2v[(2 * rp) * 64 + q * 16 + m];
        A1[k] = W2v[(2 * rp + 1) * 64 + q * 16 + m];
    }

    // ---- stage x window (swizzled), W3, v0 = w1 into LDS ----
    for (int j = tid; j < XS_LOG; j += NTHR) {
        const int g = t0 - DDEP + j;
        xs[ph(j)] = (g >= 0) ? xb[g] : 0.0f;
    }
    for (int i = tid; i < OUTD * Hd; i += NTHR) W3s[i] = W3[i];
    if (tid < Hd) Vs[tid] = w1g[tid];
    __syncthreads();

    // ---- v-chain: v_{d+1} = W2 * v_d, history kept in Vs ----
    #pragma unroll 1
    for (int d = 0; d < DDEP - 1; ++d) {
        const float4* vsrc = (const float4*)(Vs + d * Hd);
        float4 a0 = make_float4(0.f, 0.f, 0.f, 0.f);
        float4 a1 = make_float4(0.f, 0.f, 0.f, 0.f);
        #pragma unroll
        for (int k = 0; k < 16; ++k) {
            const float4 vv = vsrc[q * 16 + ((k + 4 * q) & 15)];
            a0.x = fmaf(A0[k].x, vv.x, a0.x);
            a0.y = fmaf(A0[k].y, vv.y, a0.y);
            a0.z = fmaf(A0[k].z, vv.z, a0.z);
            a0.w = fmaf(A0[k].w, vv.w, a0.w);
            a1.x = fmaf(A1[k].x, vv.x, a1.x);
            a1.y = fmaf(A1[k].y, vv.y, a1.y);
            a1.z = fmaf(A1[k].z, vv.z, a1.z);
            a1.w = fmaf(A1[k].w, vv.w, a1.w);
        }
        float p0 = (a0.x + a0.y) + (a0.z + a0.w);
        float p1 = (a1.x + a1.y) + (a1.z + a1.w);
        p0 += __shfl_xor(p0, 1);  p0 += __shfl_xor(p0, 2);
        p1 += __shfl_xor(p1, 1);  p1 += __shfl_xor(p1, 2);
        if (q == 0)
            ((float2*)(Vs + (d + 1) * Hd))[rp] = make_float2(p0, p1);
        __syncthreads();
    }

    // ---- batched K[d][o] = W3[o] . v_d : wave w does d in {w, w+8} ----
    {
        const int w = tid >> 6, l = tid & 63;
        #pragma unroll
        for (int dd = 0; dd < 2; ++dd) {
            const int d = w + dd * 8;
            const float4 vv = ((const float4*)(Vs + d * Hd))[l];
            #pragma unroll
            for (int o = 0; o < OUTD; ++o) {
                const float4 wv = ((const float4*)(W3s + o * Hd))[l];
                float p = fmaf(wv.x, vv.x,
                          fmaf(wv.y, vv.y,
                          fmaf(wv.z, vv.z, wv.w * vv.w)));
                p += __shfl_xor(p, 1);  p += __shfl_xor(p, 2);
                p += __shfl_xor(p, 4);  p += __shfl_xor(p, 8);
                p += __shfl_xor(p, 16); p += __shfl_xor(p, 32);
                if (l == 0) Ks[d * 12 + o] = p;
            }
            if (l == 1) { Ks[d * 12 + 10] = 0.f; Ks[d * 12 + 11] = 0.f; }
        }
    }
    __syncthreads();

    // ---- causal FIR: y[b,t,o] = sum_{d<16} K[d][o] * x[b,t-d]; P=4 ----
    const int ub = tid * 4;
    float acc[4][OUTD];
    #pragma unroll
    for (int i = 0; i < 4; ++i)
        #pragma unroll
        for (int o = 0; o < OUTD; ++o) acc[i][o] = 0.0f;

    float wn[4];
    #pragma unroll
    for (int i = 0; i < 4; ++i) wn[i] = xs[ph(ub + DDEP + i)];

    #pragma unroll 8
    for (int d = 0; d < DDEP; ++d) {
        const float4 kA = *(const float4*)&Ks[d * 12];
        const float4 kB = *(const float4*)&Ks[d * 12 + 4];
        const float2 kC = *(const float2*)&Ks[d * 12 + 8];
        #pragma unroll
        for (int i = 0; i < 4; ++i) {
            const float xv = wn[i];
            acc[i][0] = fmaf(kA.x, xv, acc[i][0]);
            acc[i][1] = fmaf(kA.y, xv, acc[i][1]);
            acc[i][2] = fmaf(kA.z, xv, acc[i][2]);
            acc[i][3] = fmaf(kA.w, xv, acc[i][3]);
            acc[i][4] = fmaf(kB.x, xv, acc[i][4]);
            acc[i][5] = fmaf(kB.y, xv, acc[i][5]);
            acc[i][6] = fmaf(kB.z, xv, acc[i][6]);
            acc[i][7] = fmaf(kB.w, xv, acc[i][7]);
            acc[i][8] = fmaf(kC.x, xv, acc[i][8]);
            acc[i][9] = fmaf(kC.y, xv, acc[i][9]);
        }
        const float nw = xs[ph(ub + DDEP - 1 - d)];
        wn[3] = wn[2]; wn[2] = wn[1]; wn[1] = wn[0]; wn[0] = nw;
    }

    float buf[4 * OUTD];
    #pragma unroll
    for (int i = 0; i < 4; ++i)
        #pragma unroll
        for (int o = 0; o < OUTD; ++o) buf[i * OUTD + o] = acc[i][o];

    float* yb = y + (size_t)(b * TLEN + t0 + ub) * OUTD;  // 40 consecutive floats
    #pragma unroll
    for (int v = 0; v < 10; ++v)
        *(float4*)(yb + v * 4) =
            make_float4(buf[4 * v], buf[4 * v + 1], buf[4 * v + 2], buf[4 * v + 3]);
}

extern "C" void kernel_launch(void* const* d_in, const int* in_sizes, int n_in,
                              void* d_out, int out_size, void* d_ws, size_t ws_size,
                              hipStream_t stream)
{
    const float* x  = (const float*)d_in[0];   // (64, 8192)
    const float* w1 = (const float*)d_in[1];   // (256, 1) contiguous
    const float* W2 = (const float*)d_in[2];   // (256, 256)
    const float* W3 = (const float*)d_in[3];   // (10, 256)
    float* y  = (float*)d_out;

    fused_rnn_kernel<<<NBLK, dim3(NTHR), 0, stream>>>(x, w1, W2, W3, y);
}